// Round 10
// baseline (190.591 us; speedup 1.0000x reference)
//
#include <hip/hip_runtime.h>

using short8 = __attribute__((ext_vector_type(8))) short;
using f32x4  = __attribute__((ext_vector_type(4))) float;

static constexpr int KA        = 256;    // dictionary atoms
static constexpr int PIX       = 1024;   // M*M
static constexpr int NBLK      = 256;    // cooperative blocks (1/CU)
static constexpr int NTHR      = 512;    // 8 waves, 2 col-tiles per wave (PROVEN config)
static constexpr int ROWS      = 16;     // batch rows per block
static constexpr int LDW       = 264;    // LDS row stride (shorts): 528B = 33*16 -> b128-aligned rows
static constexpr int CHW       = 16 * LDW;  // 4224 shorts per 16x256 chunk
static constexpr int MAX_ITERS = 2048;
static constexpr float LR2     = 0.2f;   // 2 * R_LR
static constexpr float LMDA_C  = 0.005f;
static constexpr float TOL2    = 1e-4f;  // TOL^2

#define AT_LOAD(p)     __hip_atomic_load((p), __ATOMIC_RELAXED, __HIP_MEMORY_SCOPE_AGENT)
#define AT_STORE(p, v) __hip_atomic_store((p), (v), __ATOMIC_RELAXED, __HIP_MEMORY_SCOPE_AGENT)

__device__ __forceinline__ unsigned short f2bf(float x) {
    unsigned u = __builtin_bit_cast(unsigned, x);
    u = (u + 0x7fffu + ((u >> 16) & 1u)) >> 16;   // RNE
    return (unsigned short)u;
}
__device__ __forceinline__ float bf2f(unsigned short h) {
    unsigned u = ((unsigned)h) << 16;
    return __builtin_bit_cast(float, u);
}
// HW RNE pack: dst[15:0]=bf16(lo), dst[31:16]=bf16(hi)
__device__ __forceinline__ unsigned cvt_pk_bf16(float lo, float hi) {
    unsigned r;
    asm("v_cvt_pk_bf16_f32 %0, %1, %2" : "=v"(r) : "v"(lo), "v"(hi));
    return r;
}

// 64-lane sum via DPP: 4x row_shr within 16-lane rows, then row_bcast15/31.
// Result valid in lane 63.
__device__ __forceinline__ float dpp_red64(float x) {
    int v;
    v = __builtin_amdgcn_update_dpp(0, __builtin_bit_cast(int, x), 0x111, 0xf, 0xf, true); // row_shr:1
    x += __builtin_bit_cast(float, v);
    v = __builtin_amdgcn_update_dpp(0, __builtin_bit_cast(int, x), 0x112, 0xf, 0xf, true); // row_shr:2
    x += __builtin_bit_cast(float, v);
    v = __builtin_amdgcn_update_dpp(0, __builtin_bit_cast(int, x), 0x114, 0xf, 0xf, true); // row_shr:4
    x += __builtin_bit_cast(float, v);
    v = __builtin_amdgcn_update_dpp(0, __builtin_bit_cast(int, x), 0x118, 0xf, 0xf, true); // row_shr:8
    x += __builtin_bit_cast(float, v);
    v = __builtin_amdgcn_update_dpp(0, __builtin_bit_cast(int, x), 0x142, 0xa, 0xf, true); // row_bcast:15
    x += __builtin_bit_cast(float, v);
    v = __builtin_amdgcn_update_dpp(0, __builtin_bit_cast(int, x), 0x143, 0xc, 0xf, true); // row_bcast:31
    x += __builtin_bit_cast(float, v);
    return x;
}

// ---------- prep ----------
// blocks 0..255   : Gram row i = b (S = U^T U); block 0 also writes sentinel
//                   tags into the tagged-partials ring (kills stale-run tags)
// blocks 256..271 : UG frag swizzle (G-GEMM B operand, tile w = b-256), hi/lo
// blocks 272..335 : UtB frag swizzle (out-GEMM B operand, tile ot = b-272), hi/lo
__global__ __launch_bounds__(256) void k_prep(const float* __restrict__ U,
                                              float* __restrict__ S,
                                              unsigned short* __restrict__ UGh,
                                              unsigned short* __restrict__ UGl,
                                              unsigned short* __restrict__ UtBh,
                                              unsigned short* __restrict__ UtBl,
                                              unsigned long long* __restrict__ partials) {
    const int t = threadIdx.x, b = blockIdx.x;
    if (b < 256) {
        if (b == 0) {
            #pragma unroll
            for (int e = 0; e < 16; ++e)
                partials[t + 256 * e] = 0xFFFFFFFF00000000ull;   // sentinel tag
        }
        __shared__ float col[PIX];
        const int i = b;
        #pragma unroll
        for (int q = 0; q < 4; ++q)
            col[t + 256 * q] = U[(size_t)(t + 256 * q) * KA + i];
        __syncthreads();
        float acc = 0.f;
        for (int p = 0; p < PIX; p += 4) {
            float4 cv = *(const float4*)&col[p];
            acc += cv.x * U[(size_t)(p + 0) * KA + t];
            acc += cv.y * U[(size_t)(p + 1) * KA + t];
            acc += cv.z * U[(size_t)(p + 2) * KA + t];
            acc += cv.w * U[(size_t)(p + 3) * KA + t];
        }
        S[(size_t)i * KA + t] = acc;
    } else if (b < 272) {
        const int w = b - 256;
        #pragma unroll 4
        for (int e = 0; e < 64; ++e) {
            const int idx = e * 256 + t;                 // (s*64+lane)*8+j
            const int s = idx >> 9, lane = (idx >> 3) & 63, j = idx & 7;
            const int k = s * 32 + ((lane >> 4) << 3) + j;
            const int c = (w << 4) + (lane & 15);
            const float x = U[(size_t)k * KA + c];
            const unsigned short hb = f2bf(x);
            UGh[w * 16384 + idx] = hb;
            UGl[w * 16384 + idx] = f2bf(x - bf2f(hb));
        }
    } else {
        const int ot = b - 272;
        #pragma unroll 4
        for (int e = 0; e < 16; ++e) {
            const int idx = e * 256 + t;                 // (s*64+lane)*8+j
            const int s = idx >> 9, lane = (idx >> 3) & 63, j = idx & 7;
            const int k = s * 32 + ((lane >> 4) << 3) + j;
            const int c = (ot << 4) + (lane & 15);
            const float x = U[(size_t)c * KA + k];       // Ut[k][c] = U[c][k]
            const unsigned short hb = f2bf(x);
            UtBh[ot * 4096 + idx] = hb;
            UtBl[ot * 4096 + idx] = f2bf(x - bf2f(hb));
        }
    }
}

#define MFMA_BF16 __builtin_amdgcn_mfma_f32_16x16x32_bf16

// ---------- fused persistent ISTA, single barrier per iteration ----------
// 8 waves; wave w owns col-tiles 2w and 2w+1 (cols [32w, 32w+32)).
// l15 = A-row m / C-col; quad = k-subgroup. C/D: row = quad*4 + i, col = base + l15.
// R10 changes vs R9:
//  (1) loop barrier = "s_waitcnt lgkmcnt(0); s_barrier" -- LDS ordering only.
//      __syncthreads' vmcnt(0) drain forced wave 7 to wait cross-L2 retirement
//      of its tagged stores every iteration; tags make that ordering unnecessary.
//  (2) soft-threshold via med3 (bit-identical, -3 VALU/elem).
//  (3) R-write bf16 conversion via v_cvt_pk_bf16_f32 (HW RNE, -20 VALU/lane).
__global__ __launch_bounds__(NTHR, 1) void k_ista(const float* __restrict__ img,
                                                  const float* __restrict__ S,
                                                  const unsigned short* __restrict__ UGh,
                                                  const unsigned short* __restrict__ UGl,
                                                  const unsigned short* __restrict__ UtBh,
                                                  const unsigned short* __restrict__ UtBl,
                                                  float* __restrict__ out,
                                                  unsigned long long* partials) {
    __shared__ __align__(16) unsigned short Ihi[4 * CHW];   // img A-frags, 4 chunks x [16][264]
    __shared__ __align__(16) unsigned short Ilo[4 * CHW];
    __shared__ __align__(16) unsigned short Rhi[2][CHW];    // R parity DB (bf16-hi only), [16][264]
    __shared__ __align__(16) unsigned short Rlo[CHW];       // epilogue-only lo buffer
    __shared__ float redL[2][16];                // per-wave num/den pairs (parity DB)
    __shared__ float red32[2][8];                // waves0-3 global-partial sums (parity DB)
    __shared__ float red40[2];                   // decision (parity DB)

    const int t    = threadIdx.x;
    const int lane = t & 63;
    const int w    = t >> 6;            // 0..7
    const int l15  = t & 15;
    const int quad = (t >> 4) & 3;
    const int colc0 = (w << 5) + l15;   // tile0 col; tile1 col = colc0 + 16
    const int blk  = blockIdx.x, row0 = blk * ROWS;

    // ---- init R=0 (both parities) + decision slots ----
    {
        unsigned short* rh = &Rhi[0][0];
        for (int idx = t; idx < 2 * CHW; idx += NTHR) rh[idx] = 0;
    }
    if (t == 0) { red40[0] = 0.f; red40[1] = 0.f; }

    // ---- stage img as split-bf16 A-frags (stride-264, conflict-free) ----
    for (int ii = t; ii < 16384; ii += NTHR) {
        const int chunk = ii >> 12, rem = ii & 4095, e = rem >> 8, kk = rem & 255;
        const float x = img[(size_t)(row0 + e) * PIX + (chunk << 8) + kk];
        const unsigned short hb = f2bf(x);
        Ihi[chunk * CHW + e * LDW + kk] = hb;
        Ilo[chunk * CHW + e * LDW + kk] = f2bf(x - bf2f(hb));
    }
    __syncthreads();

    // ---- prologue: G = img @ U via MFMA, both tiles, lands in C-layout ----
    float Gr0[4], Gr1[4];
    {
        f32x4 aH0 = {0.f,0.f,0.f,0.f}, aM0 = {0.f,0.f,0.f,0.f}, aL0 = {0.f,0.f,0.f,0.f};
        f32x4 aH1 = {0.f,0.f,0.f,0.f}, aM1 = {0.f,0.f,0.f,0.f}, aL1 = {0.f,0.f,0.f,0.f};
        const unsigned short* ugh0 = UGh + ((size_t)(2 * w) << 14) + ((size_t)lane << 3);
        const unsigned short* ugl0 = UGl + ((size_t)(2 * w) << 14) + ((size_t)lane << 3);
        const unsigned short* ugh1 = ugh0 + 16384;
        const unsigned short* ugl1 = ugl0 + 16384;
        #pragma unroll
        for (int s = 0; s < 32; ++s) {
            const int ab = (s >> 3) * CHW + l15 * LDW + (s & 7) * 32 + (quad << 3);
            const short8 ah = *(const short8*)&Ihi[ab];
            const short8 al = *(const short8*)&Ilo[ab];
            const short8 bh0 = *(const short8*)&ugh0[(size_t)s << 9];
            const short8 bl0 = *(const short8*)&ugl0[(size_t)s << 9];
            const short8 bh1 = *(const short8*)&ugh1[(size_t)s << 9];
            const short8 bl1 = *(const short8*)&ugl1[(size_t)s << 9];
            aH0 = MFMA_BF16(ah, bh0, aH0, 0, 0, 0);
            aM0 = MFMA_BF16(ah, bl0, aM0, 0, 0, 0);
            aL0 = MFMA_BF16(al, bh0, aL0, 0, 0, 0);
            aH1 = MFMA_BF16(ah, bh1, aH1, 0, 0, 0);
            aM1 = MFMA_BF16(ah, bl1, aM1, 0, 0, 0);
            aL1 = MFMA_BF16(al, bh1, aL1, 0, 0, 0);
        }
        #pragma unroll
        for (int i = 0; i < 4; ++i) {
            Gr0[i] = (aH0[i] + aM0[i]) + aL0[i];
            Gr1[i] = (aH1[i] + aM1[i]) + aL1[i];
        }
    }

    // ---- S B-fragments: split-bf16, register-resident, 2 tiles ----
    short8 Bh0[8], Bl0[8], Bh1[8], Bl1[8];
    #pragma unroll
    for (int s = 0; s < 8; ++s) {
        #pragma unroll
        for (int j = 0; j < 8; ++j) {
            const int kr = (s << 5) + (quad << 3) + j;
            const float x0 = S[(size_t)kr * KA + colc0];
            const unsigned short h0 = f2bf(x0);
            Bh0[s][j] = (short)h0;
            Bl0[s][j] = (short)f2bf(x0 - bf2f(h0));
            const float x1 = S[(size_t)kr * KA + colc0 + 16];
            const unsigned short h1 = f2bf(x1);
            Bh1[s][j] = (short)h1;
            Bl1[s][j] = (short)f2bf(x1 - bf2f(h1));
        }
    }

    float Rold0[4] = {0.f, 0.f, 0.f, 0.f}, Rold1[4] = {0.f, 0.f, 0.f, 0.f};
    float sn0[8] = {0.f}, sn1[8] = {0.f}, sn2[8] = {0.f}, sn3[8] = {0.f};
    bool fired = false;
    int fslot = 0;

    // ================= ISTA loop: ONE barrier per iteration =================
    for (int iter = 0; iter < MAX_ITERS; ++iter) {
        // LDS-only barrier: order R[par]/redL/red32/red40 without draining the
        // tagged global stores (tags carry their own validity).
        asm volatile("s_waitcnt lgkmcnt(0)\n\ts_barrier" ::: "memory");
        if (red40[(iter + 1) & 1] != 0.f) { fired = true; fslot = iter & 3; break; }

        const int par = iter & 1;

        // ---- housekeeping on wave 7 lane 0: runs in parallel with MFMA waves ----
        if (t == 448) {
            if (iter >= 1) {
                const float* rl = redL[par ^ 1];
                float n = 0.f, d = 0.f;
                #pragma unroll
                for (int i = 0; i < 8; ++i) { n += rl[2 * i]; d += rl[2 * i + 1]; }
                const unsigned long long tg = ((unsigned long long)(unsigned)(iter - 1)) << 32;
                unsigned long long* pdst = partials + (size_t)((iter - 1) & 7) * (2 * NBLK) + blk * 2;
                AT_STORE(&pdst[0], tg | (unsigned long long)__builtin_bit_cast(unsigned, n));
                AT_STORE(&pdst[1], tg | (unsigned long long)__builtin_bit_cast(unsigned, d));
            }
            if (iter >= 4) {  // decision for ratio_{iter-4}, identical order in every block
                const float* r3 = red32[par ^ 1];
                const float gn = (r3[0] + r3[2]) + (r3[4] + r3[6]);
                const float gd = (r3[1] + r3[3]) + (r3[5] + r3[7]);
                red40[par] = (gn < TOL2 * gd) ? 1.f : 0.f;
            }
        }

        // ---- gather of ratio_{iter-3} tagged partials: issue loads NOW,
        //      validate after the GEMM (drain hides under compute) ----
        const bool chk = (iter >= 3) && (t < 256);
        const unsigned want = (unsigned)(iter - 3);
        const unsigned long long* ps = partials + (size_t)(want & 7) * (2 * NBLK);
        unsigned long long pn = 0, pd = 0;
        if (chk) {
            pn = AT_LOAD(&ps[t * 2 + 0]);
            pd = AT_LOAD(&ps[t * 2 + 1]);
        }
        asm volatile("" ::: "memory");   // pin the issue point above the GEMM

        // ---- a = R*S via bf16-R x split-bf16-S MFMA, 2 tiles x 2 chains ----
        f32x4 aH0 = {0.f,0.f,0.f,0.f}, aM0 = {0.f,0.f,0.f,0.f};
        f32x4 aH1 = {0.f,0.f,0.f,0.f}, aM1 = {0.f,0.f,0.f,0.f};
        const int arow = l15 * LDW;
        #pragma unroll
        for (int s = 0; s < 8; ++s) {
            const int ab = arow + (s << 5) + (quad << 3);
            const short8 ah = *(const short8*)&Rhi[par][ab];
            aH0 = MFMA_BF16(ah, Bh0[s], aH0, 0, 0, 0);
            aM0 = MFMA_BF16(ah, Bl0[s], aM0, 0, 0, 0);
            aH1 = MFMA_BF16(ah, Bh1[s], aH1, 0, 0, 0);
            aM1 = MFMA_BF16(ah, Bl1[s], aM1, 0, 0, 0);
        }

        // ---- shrink (med3) + num/den; write parity^1 (hi only, cvt_pk) ----
        float num = 0.f, den = 0.f, Nn0[4], Nn1[4];
        #pragma unroll
        for (int i = 0; i < 4; ++i) {
            const float av0 = aH0[i] + aM0[i];
            const float v0 = Rold0[i] + LR2 * (Gr0[i] - av0);
            const float n0 = v0 - fminf(fmaxf(v0, -LMDA_C), LMDA_C);   // v_med3
            const float d0 = n0 - Rold0[i];
            num += d0 * d0; den += Rold0[i] * Rold0[i];
            Nn0[i] = n0;
            const float av1 = aH1[i] + aM1[i];
            const float v1 = Rold1[i] + LR2 * (Gr1[i] - av1);
            const float n1 = v1 - fminf(fmaxf(v1, -LMDA_C), LMDA_C);   // v_med3
            const float d1 = n1 - Rold1[i];
            num += d1 * d1; den += Rold1[i] * Rold1[i];
            Nn1[i] = n1;
        }
        #pragma unroll
        for (int i = 0; i < 4; ++i) {
            const int idx = ((quad << 2) + i) * LDW + colc0;
            const unsigned pk = cvt_pk_bf16(Nn0[i], Nn1[i]);
            Rhi[par ^ 1][idx]      = (unsigned short)(pk & 0xffffu);
            Rhi[par ^ 1][idx + 16] = (unsigned short)(pk >> 16);
        }

        // ---- validate tags; re-poll only mismatched lanes (rare) ----
        float gsn = 0.f, gsd = 0.f;
        if (chk) {
            while (__any(((unsigned)(pn >> 32) != want) || ((unsigned)(pd >> 32) != want))) {
                __builtin_amdgcn_s_sleep(2);
                if ((unsigned)(pn >> 32) != want) pn = AT_LOAD(&ps[t * 2 + 0]);
                if ((unsigned)(pd >> 32) != want) pd = AT_LOAD(&ps[t * 2 + 1]);
            }
            gsn = __builtin_bit_cast(float, (unsigned)(pn & 0xFFFFFFFFull));
            gsd = __builtin_bit_cast(float, (unsigned)(pd & 0xFFFFFFFFull));
        }

        // ---- local reduce (DPP) -> redL[par]; gather -> red32[par] ----
        num = dpp_red64(num);
        den = dpp_red64(den);
        if (lane == 63) { redL[par][w * 2] = num; redL[par][w * 2 + 1] = den; }
        if (chk) {
            gsn = dpp_red64(gsn);
            gsd = dpp_red64(gsd);
            if (lane == 63) { red32[par][w * 2] = gsn; red32[par][w * 2 + 1] = gsd; }
        }

        // ---- snapshot ring (wave-uniform switch, no rotation) ----
        const int sq = iter & 3;
        if (sq == 0) {
            sn0[0]=Rold0[0]; sn0[1]=Rold0[1]; sn0[2]=Rold0[2]; sn0[3]=Rold0[3];
            sn0[4]=Rold1[0]; sn0[5]=Rold1[1]; sn0[6]=Rold1[2]; sn0[7]=Rold1[3];
        } else if (sq == 1) {
            sn1[0]=Rold0[0]; sn1[1]=Rold0[1]; sn1[2]=Rold0[2]; sn1[3]=Rold0[3];
            sn1[4]=Rold1[0]; sn1[5]=Rold1[1]; sn1[6]=Rold1[2]; sn1[7]=Rold1[3];
        } else if (sq == 2) {
            sn2[0]=Rold0[0]; sn2[1]=Rold0[1]; sn2[2]=Rold0[2]; sn2[3]=Rold0[3];
            sn2[4]=Rold1[0]; sn2[5]=Rold1[1]; sn2[6]=Rold1[2]; sn2[7]=Rold1[3];
        } else {
            sn3[0]=Rold0[0]; sn3[1]=Rold0[1]; sn3[2]=Rold0[2]; sn3[3]=Rold0[3];
            sn3[4]=Rold1[0]; sn3[5]=Rold1[1]; sn3[6]=Rold1[2]; sn3[7]=Rold1[3];
        }
        #pragma unroll
        for (int i = 0; i < 4; ++i) { Rold0[i] = Nn0[i]; Rold1[i] = Nn1[i]; }
    }

    // ---- final R (fired at b: ratio_{b-5} < TOL -> output R_{b-4} = slot b&3) ----
    float Rf0[4], Rf1[4];
    if (!fired) {
        #pragma unroll
        for (int i = 0; i < 4; ++i) { Rf0[i] = Rold0[i]; Rf1[i] = Rold1[i]; }
    } else if (fslot == 0) {
        #pragma unroll
        for (int i = 0; i < 4; ++i) { Rf0[i] = sn0[i]; Rf1[i] = sn0[4 + i]; }
    } else if (fslot == 1) {
        #pragma unroll
        for (int i = 0; i < 4; ++i) { Rf0[i] = sn1[i]; Rf1[i] = sn1[4 + i]; }
    } else if (fslot == 2) {
        #pragma unroll
        for (int i = 0; i < 4; ++i) { Rf0[i] = sn2[i]; Rf1[i] = sn2[4 + i]; }
    } else {
        #pragma unroll
        for (int i = 0; i < 4; ++i) { Rf0[i] = sn3[i]; Rf1[i] = sn3[4 + i]; }
    }

    // ---- write final R as hi+lo (full precision for the output GEMM) ----
    #pragma unroll
    for (int i = 0; i < 4; ++i) {
        const int idx = ((quad << 2) + i) * LDW + colc0;
        const unsigned short h0 = f2bf(Rf0[i]);
        Rhi[0][idx] = h0;
        Rlo[idx]    = f2bf(Rf0[i] - bf2f(h0));
        const unsigned short h1 = f2bf(Rf1[i]);
        Rhi[0][idx + 16] = h1;
        Rlo[idx + 16]    = f2bf(Rf1[i] - bf2f(h1));
    }
    __syncthreads();

    // ---- epilogue: out = R @ Ut via MFMA (8 tiles/wave), 3 chains ----
    #pragma unroll
    for (int tt = 0; tt < 8; ++tt) {
        const int ot = tt * 8 + w;
        f32x4 aH = {0.f,0.f,0.f,0.f}, aM = {0.f,0.f,0.f,0.f}, aL = {0.f,0.f,0.f,0.f};
        const unsigned short* ubh = UtBh + (size_t)ot * 4096 + ((size_t)lane << 3);
        const unsigned short* ubl = UtBl + (size_t)ot * 4096 + ((size_t)lane << 3);
        #pragma unroll
        for (int s = 0; s < 8; ++s) {
            const int ab = l15 * LDW + (s << 5) + (quad << 3);
            const short8 ah = *(const short8*)&Rhi[0][ab];
            const short8 al = *(const short8*)&Rlo[ab];
            const short8 bh = *(const short8*)&ubh[(size_t)s << 9];
            const short8 bl = *(const short8*)&ubl[(size_t)s << 9];
            aH = MFMA_BF16(ah, bh, aH, 0, 0, 0);
            aM = MFMA_BF16(ah, bl, aM, 0, 0, 0);
            aL = MFMA_BF16(al, bh, aL, 0, 0, 0);
        }
        #pragma unroll
        for (int i = 0; i < 4; ++i)
            out[(size_t)(row0 + (quad << 2) + i) * PIX + (ot << 4) + l15] =
                (aH[i] + aM[i]) + aL[i];
    }
}

extern "C" void kernel_launch(void* const* d_in, const int* in_sizes, int n_in,
                              void* d_out, int out_size, void* d_ws, size_t ws_size,
                              hipStream_t stream) {
    const float* img = (const float*)d_in[0];  // [4096, 1024]
    const float* U   = (const float*)d_in[1];  // [1024, 256]
    float* out = (float*)d_out;                // [4096, 1024]

    float*          S     = (float*)d_ws;                       // 65536 f (256 KB)
    unsigned short* UGh   = (unsigned short*)((char*)d_ws + 262144);   // 512 KB
    unsigned short* UGl   = UGh + 262144;                              // 512 KB
    unsigned short* UtBh  = UGl + 262144;                              // 512 KB
    unsigned short* UtBl  = UtBh + 262144;                             // 512 KB
    unsigned long long* partials = (unsigned long long*)(UtBl + 262144); // 8*2*256 u64 = 32 KB

    k_prep<<<336, 256, 0, stream>>>(U, S, UGh, UGl, UtBh, UtBl, partials);

    void* args[] = {(void*)&img, (void*)&S, (void*)&UGh, (void*)&UGl,
                    (void*)&UtBh, (void*)&UtBl, (void*)&out, (void*)&partials};
    hipLaunchCooperativeKernel((void*)k_ista, dim3(NBLK), dim3(NTHR), args, 0, stream);
}

// Round 13
// 166.046 us; speedup vs baseline: 1.1478x; 1.1478x over previous
//
#include <hip/hip_runtime.h>

using short8 = __attribute__((ext_vector_type(8))) short;
using f32x4  = __attribute__((ext_vector_type(4))) float;

static constexpr int KA        = 256;    // dictionary atoms
static constexpr int PIX       = 1024;   // M*M
static constexpr int NBLK      = 256;    // blocks (1/CU -> all co-resident)
static constexpr int NTHR      = 512;    // 8 waves, 2 col-tiles per wave (PROVEN config)
static constexpr int ROWS      = 16;     // batch rows per block
static constexpr int LDW       = 264;    // LDS row stride (shorts): 528B = 33*16 -> b128-aligned rows
static constexpr int CHW       = 16 * LDW;  // 4224 shorts per 16x256 chunk
static constexpr int MAX_ITERS = 2048;
static constexpr float LR2     = 0.2f;   // 2 * R_LR
static constexpr float LMDA_C  = 0.005f;
static constexpr float TOL2    = 1e-4f;  // TOL^2

#define AT_LOAD(p)     __hip_atomic_load((p), __ATOMIC_RELAXED, __HIP_MEMORY_SCOPE_AGENT)
#define AT_STORE(p, v) __hip_atomic_store((p), (v), __ATOMIC_RELAXED, __HIP_MEMORY_SCOPE_AGENT)

__device__ __forceinline__ unsigned short f2bf(float x) {
    unsigned u = __builtin_bit_cast(unsigned, x);
    u = (u + 0x7fffu + ((u >> 16) & 1u)) >> 16;   // RNE
    return (unsigned short)u;
}
__device__ __forceinline__ float bf2f(unsigned short h) {
    unsigned u = ((unsigned)h) << 16;
    return __builtin_bit_cast(float, u);
}
// HW RNE pack: dst[15:0]=bf16(lo), dst[31:16]=bf16(hi)
__device__ __forceinline__ unsigned cvt_pk_bf16(float lo, float hi) {
    unsigned r;
    asm("v_cvt_pk_bf16_f32 %0, %1, %2" : "=v"(r) : "v"(lo), "v"(hi));
    return r;
}

// 64-lane sum via DPP: 4x row_shr within 16-lane rows, then row_bcast15/31.
// Result valid in lane 63.
__device__ __forceinline__ float dpp_red64(float x) {
    int v;
    v = __builtin_amdgcn_update_dpp(0, __builtin_bit_cast(int, x), 0x111, 0xf, 0xf, true); // row_shr:1
    x += __builtin_bit_cast(float, v);
    v = __builtin_amdgcn_update_dpp(0, __builtin_bit_cast(int, x), 0x112, 0xf, 0xf, true); // row_shr:2
    x += __builtin_bit_cast(float, v);
    v = __builtin_amdgcn_update_dpp(0, __builtin_bit_cast(int, x), 0x114, 0xf, 0xf, true); // row_shr:4
    x += __builtin_bit_cast(float, v);
    v = __builtin_amdgcn_update_dpp(0, __builtin_bit_cast(int, x), 0x118, 0xf, 0xf, true); // row_shr:8
    x += __builtin_bit_cast(float, v);
    v = __builtin_amdgcn_update_dpp(0, __builtin_bit_cast(int, x), 0x142, 0xa, 0xf, true); // row_bcast:15
    x += __builtin_bit_cast(float, v);
    v = __builtin_amdgcn_update_dpp(0, __builtin_bit_cast(int, x), 0x143, 0xc, 0xf, true); // row_bcast:31
    x += __builtin_bit_cast(float, v);
    return x;
}

// ---------- prep ----------
// blocks 0..255   : Gram row i = b (S = U^T U); block 0 also writes sentinel
//                   tags into the tagged-partials ring (kills stale-run tags)
// blocks 256..271 : UG frag swizzle (G-GEMM B operand, tile w = b-256), hi/lo
// blocks 272..335 : UtB frag swizzle (out-GEMM B operand, tile ot = b-272), hi/lo
__global__ __launch_bounds__(256) void k_prep(const float* __restrict__ U,
                                              float* __restrict__ S,
                                              unsigned short* __restrict__ UGh,
                                              unsigned short* __restrict__ UGl,
                                              unsigned short* __restrict__ UtBh,
                                              unsigned short* __restrict__ UtBl,
                                              unsigned long long* __restrict__ partials) {
    const int t = threadIdx.x, b = blockIdx.x;
    if (b < 256) {
        if (b == 0) {
            #pragma unroll
            for (int e = 0; e < 16; ++e)
                partials[t + 256 * e] = 0xFFFFFFFF00000000ull;   // sentinel tag
        }
        __shared__ float col[PIX];
        const int i = b;
        #pragma unroll
        for (int q = 0; q < 4; ++q)
            col[t + 256 * q] = U[(size_t)(t + 256 * q) * KA + i];
        __syncthreads();
        float acc = 0.f;
        for (int p = 0; p < PIX; p += 4) {
            float4 cv = *(const float4*)&col[p];
            acc += cv.x * U[(size_t)(p + 0) * KA + t];
            acc += cv.y * U[(size_t)(p + 1) * KA + t];
            acc += cv.z * U[(size_t)(p + 2) * KA + t];
            acc += cv.w * U[(size_t)(p + 3) * KA + t];
        }
        S[(size_t)i * KA + t] = acc;
    } else if (b < 272) {
        const int w = b - 256;
        #pragma unroll 4
        for (int e = 0; e < 64; ++e) {
            const int idx = e * 256 + t;                 // (s*64+lane)*8+j
            const int s = idx >> 9, lane = (idx >> 3) & 63, j = idx & 7;
            const int k = s * 32 + ((lane >> 4) << 3) + j;
            const int c = (w << 4) + (lane & 15);
            const float x = U[(size_t)k * KA + c];
            const unsigned short hb = f2bf(x);
            UGh[w * 16384 + idx] = hb;
            UGl[w * 16384 + idx] = f2bf(x - bf2f(hb));
        }
    } else {
        const int ot = b - 272;
        #pragma unroll 4
        for (int e = 0; e < 16; ++e) {
            const int idx = e * 256 + t;                 // (s*64+lane)*8+j
            const int s = idx >> 9, lane = (idx >> 3) & 63, j = idx & 7;
            const int k = s * 32 + ((lane >> 4) << 3) + j;
            const int c = (ot << 4) + (lane & 15);
            const float x = U[(size_t)c * KA + k];       // Ut[k][c] = U[c][k]
            const unsigned short hb = f2bf(x);
            UtBh[ot * 4096 + idx] = hb;
            UtBl[ot * 4096 + idx] = f2bf(x - bf2f(hb));
        }
    }
}

#define MFMA_BF16 __builtin_amdgcn_mfma_f32_16x16x32_bf16

// ---------- fused persistent ISTA, single barrier per iteration ----------
// 8 waves; wave w owns col-tiles 2w and 2w+1 (cols [32w, 32w+32)).
// l15 = A-row m / C-col; quad = k-subgroup. C/D: row = quad*4 + i, col = base + l15.
// R13 = R10 VERBATIM kernel (proven numerics: fire-check and housekeeping at
// loop top -- R11/R12 showed moving them flips a borderline convergence
// decision). Only the LAUNCH changed: regular launch instead of cooperative.
// The kernel uses no grid barrier -- all inter-block comm is the tagged
// protocol with spin-retry -- and at 256 blocks x 1/CU all are co-resident.
__global__ __launch_bounds__(NTHR, 1) void k_ista(const float* __restrict__ img,
                                                  const float* __restrict__ S,
                                                  const unsigned short* __restrict__ UGh,
                                                  const unsigned short* __restrict__ UGl,
                                                  const unsigned short* __restrict__ UtBh,
                                                  const unsigned short* __restrict__ UtBl,
                                                  float* __restrict__ out,
                                                  unsigned long long* partials) {
    __shared__ __align__(16) unsigned short Ihi[4 * CHW];   // img A-frags, 4 chunks x [16][264]
    __shared__ __align__(16) unsigned short Ilo[4 * CHW];
    __shared__ __align__(16) unsigned short Rhi[2][CHW];    // R parity DB (bf16-hi only), [16][264]
    __shared__ __align__(16) unsigned short Rlo[CHW];       // epilogue-only lo buffer
    __shared__ float redL[2][16];                // per-wave num/den pairs (parity DB)
    __shared__ float red32[2][8];                // waves0-3 global-partial sums (parity DB)
    __shared__ float red40[2];                   // decision (parity DB)

    const int t    = threadIdx.x;
    const int lane = t & 63;
    const int w    = t >> 6;            // 0..7
    const int l15  = t & 15;
    const int quad = (t >> 4) & 3;
    const int colc0 = (w << 5) + l15;   // tile0 col; tile1 col = colc0 + 16
    const int blk  = blockIdx.x, row0 = blk * ROWS;

    // ---- init R=0 (both parities) + decision slots ----
    {
        unsigned short* rh = &Rhi[0][0];
        for (int idx = t; idx < 2 * CHW; idx += NTHR) rh[idx] = 0;
    }
    if (t == 0) { red40[0] = 0.f; red40[1] = 0.f; }

    // ---- stage img as split-bf16 A-frags (stride-264, conflict-free) ----
    for (int ii = t; ii < 16384; ii += NTHR) {
        const int chunk = ii >> 12, rem = ii & 4095, e = rem >> 8, kk = rem & 255;
        const float x = img[(size_t)(row0 + e) * PIX + (chunk << 8) + kk];
        const unsigned short hb = f2bf(x);
        Ihi[chunk * CHW + e * LDW + kk] = hb;
        Ilo[chunk * CHW + e * LDW + kk] = f2bf(x - bf2f(hb));
    }
    __syncthreads();

    // ---- prologue: G = img @ U via MFMA, both tiles, lands in C-layout ----
    float Gr0[4], Gr1[4];
    {
        f32x4 aH0 = {0.f,0.f,0.f,0.f}, aM0 = {0.f,0.f,0.f,0.f}, aL0 = {0.f,0.f,0.f,0.f};
        f32x4 aH1 = {0.f,0.f,0.f,0.f}, aM1 = {0.f,0.f,0.f,0.f}, aL1 = {0.f,0.f,0.f,0.f};
        const unsigned short* ugh0 = UGh + ((size_t)(2 * w) << 14) + ((size_t)lane << 3);
        const unsigned short* ugl0 = UGl + ((size_t)(2 * w) << 14) + ((size_t)lane << 3);
        const unsigned short* ugh1 = ugh0 + 16384;
        const unsigned short* ugl1 = ugl0 + 16384;
        #pragma unroll
        for (int s = 0; s < 32; ++s) {
            const int ab = (s >> 3) * CHW + l15 * LDW + (s & 7) * 32 + (quad << 3);
            const short8 ah = *(const short8*)&Ihi[ab];
            const short8 al = *(const short8*)&Ilo[ab];
            const short8 bh0 = *(const short8*)&ugh0[(size_t)s << 9];
            const short8 bl0 = *(const short8*)&ugl0[(size_t)s << 9];
            const short8 bh1 = *(const short8*)&ugh1[(size_t)s << 9];
            const short8 bl1 = *(const short8*)&ugl1[(size_t)s << 9];
            aH0 = MFMA_BF16(ah, bh0, aH0, 0, 0, 0);
            aM0 = MFMA_BF16(ah, bl0, aM0, 0, 0, 0);
            aL0 = MFMA_BF16(al, bh0, aL0, 0, 0, 0);
            aH1 = MFMA_BF16(ah, bh1, aH1, 0, 0, 0);
            aM1 = MFMA_BF16(ah, bl1, aM1, 0, 0, 0);
            aL1 = MFMA_BF16(al, bh1, aL1, 0, 0, 0);
        }
        #pragma unroll
        for (int i = 0; i < 4; ++i) {
            Gr0[i] = (aH0[i] + aM0[i]) + aL0[i];
            Gr1[i] = (aH1[i] + aM1[i]) + aL1[i];
        }
    }

    // ---- S B-fragments: split-bf16, register-resident, 2 tiles ----
    short8 Bh0[8], Bl0[8], Bh1[8], Bl1[8];
    #pragma unroll
    for (int s = 0; s < 8; ++s) {
        #pragma unroll
        for (int j = 0; j < 8; ++j) {
            const int kr = (s << 5) + (quad << 3) + j;
            const float x0 = S[(size_t)kr * KA + colc0];
            const unsigned short h0 = f2bf(x0);
            Bh0[s][j] = (short)h0;
            Bl0[s][j] = (short)f2bf(x0 - bf2f(h0));
            const float x1 = S[(size_t)kr * KA + colc0 + 16];
            const unsigned short h1 = f2bf(x1);
            Bh1[s][j] = (short)h1;
            Bl1[s][j] = (short)f2bf(x1 - bf2f(h1));
        }
    }

    float Rold0[4] = {0.f, 0.f, 0.f, 0.f}, Rold1[4] = {0.f, 0.f, 0.f, 0.f};
    float sn0[8] = {0.f}, sn1[8] = {0.f}, sn2[8] = {0.f}, sn3[8] = {0.f};
    bool fired = false;
    int fslot = 0;

    // ================= ISTA loop: ONE barrier per iteration =================
    for (int iter = 0; iter < MAX_ITERS; ++iter) {
        // LDS-only barrier: order R[par]/redL/red32/red40 without draining the
        // tagged global stores (tags carry their own validity).
        asm volatile("s_waitcnt lgkmcnt(0)\n\ts_barrier" ::: "memory");
        if (red40[(iter + 1) & 1] != 0.f) { fired = true; fslot = iter & 3; break; }

        const int par = iter & 1;

        // ---- housekeeping on wave 7 lane 0: runs in parallel with MFMA waves ----
        if (t == 448) {
            if (iter >= 1) {
                const float* rl = redL[par ^ 1];
                float n = 0.f, d = 0.f;
                #pragma unroll
                for (int i = 0; i < 8; ++i) { n += rl[2 * i]; d += rl[2 * i + 1]; }
                const unsigned long long tg = ((unsigned long long)(unsigned)(iter - 1)) << 32;
                unsigned long long* pdst = partials + (size_t)((iter - 1) & 7) * (2 * NBLK) + blk * 2;
                AT_STORE(&pdst[0], tg | (unsigned long long)__builtin_bit_cast(unsigned, n));
                AT_STORE(&pdst[1], tg | (unsigned long long)__builtin_bit_cast(unsigned, d));
            }
            if (iter >= 4) {  // decision for ratio_{iter-4}, identical order in every block
                const float* r3 = red32[par ^ 1];
                const float gn = (r3[0] + r3[2]) + (r3[4] + r3[6]);
                const float gd = (r3[1] + r3[3]) + (r3[5] + r3[7]);
                red40[par] = (gn < TOL2 * gd) ? 1.f : 0.f;
            }
        }

        // ---- gather of ratio_{iter-3} tagged partials: issue loads NOW,
        //      validate after the GEMM (drain hides under compute) ----
        const bool chk = (iter >= 3) && (t < 256);
        const unsigned want = (unsigned)(iter - 3);
        const unsigned long long* ps = partials + (size_t)(want & 7) * (2 * NBLK);
        unsigned long long pn = 0, pd = 0;
        if (chk) {
            pn = AT_LOAD(&ps[t * 2 + 0]);
            pd = AT_LOAD(&ps[t * 2 + 1]);
        }
        asm volatile("" ::: "memory");   // pin the issue point above the GEMM

        // ---- a = R*S via bf16-R x split-bf16-S MFMA, 2 tiles x 2 chains ----
        f32x4 aH0 = {0.f,0.f,0.f,0.f}, aM0 = {0.f,0.f,0.f,0.f};
        f32x4 aH1 = {0.f,0.f,0.f,0.f}, aM1 = {0.f,0.f,0.f,0.f};
        const int arow = l15 * LDW;
        #pragma unroll
        for (int s = 0; s < 8; ++s) {
            const int ab = arow + (s << 5) + (quad << 3);
            const short8 ah = *(const short8*)&Rhi[par][ab];
            aH0 = MFMA_BF16(ah, Bh0[s], aH0, 0, 0, 0);
            aM0 = MFMA_BF16(ah, Bl0[s], aM0, 0, 0, 0);
            aH1 = MFMA_BF16(ah, Bh1[s], aH1, 0, 0, 0);
            aM1 = MFMA_BF16(ah, Bl1[s], aM1, 0, 0, 0);
        }

        // ---- shrink (med3) + num/den; write parity^1 (hi only, cvt_pk) ----
        float num = 0.f, den = 0.f, Nn0[4], Nn1[4];
        #pragma unroll
        for (int i = 0; i < 4; ++i) {
            const float av0 = aH0[i] + aM0[i];
            const float v0 = Rold0[i] + LR2 * (Gr0[i] - av0);
            const float n0 = v0 - fminf(fmaxf(v0, -LMDA_C), LMDA_C);   // v_med3
            const float d0 = n0 - Rold0[i];
            num += d0 * d0; den += Rold0[i] * Rold0[i];
            Nn0[i] = n0;
            const float av1 = aH1[i] + aM1[i];
            const float v1 = Rold1[i] + LR2 * (Gr1[i] - av1);
            const float n1 = v1 - fminf(fmaxf(v1, -LMDA_C), LMDA_C);   // v_med3
            const float d1 = n1 - Rold1[i];
            num += d1 * d1; den += Rold1[i] * Rold1[i];
            Nn1[i] = n1;
        }
        #pragma unroll
        for (int i = 0; i < 4; ++i) {
            const int idx = ((quad << 2) + i) * LDW + colc0;
            const unsigned pk = cvt_pk_bf16(Nn0[i], Nn1[i]);
            Rhi[par ^ 1][idx]      = (unsigned short)(pk & 0xffffu);
            Rhi[par ^ 1][idx + 16] = (unsigned short)(pk >> 16);
        }

        // ---- validate tags; re-poll only mismatched lanes (rare) ----
        float gsn = 0.f, gsd = 0.f;
        if (chk) {
            while (__any(((unsigned)(pn >> 32) != want) || ((unsigned)(pd >> 32) != want))) {
                __builtin_amdgcn_s_sleep(2);
                if ((unsigned)(pn >> 32) != want) pn = AT_LOAD(&ps[t * 2 + 0]);
                if ((unsigned)(pd >> 32) != want) pd = AT_LOAD(&ps[t * 2 + 1]);
            }
            gsn = __builtin_bit_cast(float, (unsigned)(pn & 0xFFFFFFFFull));
            gsd = __builtin_bit_cast(float, (unsigned)(pd & 0xFFFFFFFFull));
        }

        // ---- local reduce (DPP) -> redL[par]; gather -> red32[par] ----
        num = dpp_red64(num);
        den = dpp_red64(den);
        if (lane == 63) { redL[par][w * 2] = num; redL[par][w * 2 + 1] = den; }
        if (chk) {
            gsn = dpp_red64(gsn);
            gsd = dpp_red64(gsd);
            if (lane == 63) { red32[par][w * 2] = gsn; red32[par][w * 2 + 1] = gsd; }
        }

        // ---- snapshot ring (wave-uniform switch, no rotation) ----
        const int sq = iter & 3;
        if (sq == 0) {
            sn0[0]=Rold0[0]; sn0[1]=Rold0[1]; sn0[2]=Rold0[2]; sn0[3]=Rold0[3];
            sn0[4]=Rold1[0]; sn0[5]=Rold1[1]; sn0[6]=Rold1[2]; sn0[7]=Rold1[3];
        } else if (sq == 1) {
            sn1[0]=Rold0[0]; sn1[1]=Rold0[1]; sn1[2]=Rold0[2]; sn1[3]=Rold0[3];
            sn1[4]=Rold1[0]; sn1[5]=Rold1[1]; sn1[6]=Rold1[2]; sn1[7]=Rold1[3];
        } else if (sq == 2) {
            sn2[0]=Rold0[0]; sn2[1]=Rold0[1]; sn2[2]=Rold0[2]; sn2[3]=Rold0[3];
            sn2[4]=Rold1[0]; sn2[5]=Rold1[1]; sn2[6]=Rold1[2]; sn2[7]=Rold1[3];
        } else {
            sn3[0]=Rold0[0]; sn3[1]=Rold0[1]; sn3[2]=Rold0[2]; sn3[3]=Rold0[3];
            sn3[4]=Rold1[0]; sn3[5]=Rold1[1]; sn3[6]=Rold1[2]; sn3[7]=Rold1[3];
        }
        #pragma unroll
        for (int i = 0; i < 4; ++i) { Rold0[i] = Nn0[i]; Rold1[i] = Nn1[i]; }
    }

    // ---- final R (fired at b: ratio_{b-5} < TOL -> output R_{b-4} = slot b&3) ----
    float Rf0[4], Rf1[4];
    if (!fired) {
        #pragma unroll
        for (int i = 0; i < 4; ++i) { Rf0[i] = Rold0[i]; Rf1[i] = Rold1[i]; }
    } else if (fslot == 0) {
        #pragma unroll
        for (int i = 0; i < 4; ++i) { Rf0[i] = sn0[i]; Rf1[i] = sn0[4 + i]; }
    } else if (fslot == 1) {
        #pragma unroll
        for (int i = 0; i < 4; ++i) { Rf0[i] = sn1[i]; Rf1[i] = sn1[4 + i]; }
    } else if (fslot == 2) {
        #pragma unroll
        for (int i = 0; i < 4; ++i) { Rf0[i] = sn2[i]; Rf1[i] = sn2[4 + i]; }
    } else {
        #pragma unroll
        for (int i = 0; i < 4; ++i) { Rf0[i] = sn3[i]; Rf1[i] = sn3[4 + i]; }
    }

    // ---- write final R as hi+lo (full precision for the output GEMM) ----
    #pragma unroll
    for (int i = 0; i < 4; ++i) {
        const int idx = ((quad << 2) + i) * LDW + colc0;
        const unsigned short h0 = f2bf(Rf0[i]);
        Rhi[0][idx] = h0;
        Rlo[idx]    = f2bf(Rf0[i] - bf2f(h0));
        const unsigned short h1 = f2bf(Rf1[i]);
        Rhi[0][idx + 16] = h1;
        Rlo[idx + 16]    = f2bf(Rf1[i] - bf2f(h1));
    }
    __syncthreads();

    // ---- epilogue: out = R @ Ut via MFMA (8 tiles/wave), 3 chains ----
    #pragma unroll
    for (int tt = 0; tt < 8; ++tt) {
        const int ot = tt * 8 + w;
        f32x4 aH = {0.f,0.f,0.f,0.f}, aM = {0.f,0.f,0.f,0.f}, aL = {0.f,0.f,0.f,0.f};
        const unsigned short* ubh = UtBh + (size_t)ot * 4096 + ((size_t)lane << 3);
        const unsigned short* ubl = UtBl + (size_t)ot * 4096 + ((size_t)lane << 3);
        #pragma unroll
        for (int s = 0; s < 8; ++s) {
            const int ab = l15 * LDW + (s << 5) + (quad << 3);
            const short8 ah = *(const short8*)&Rhi[0][ab];
            const short8 al = *(const short8*)&Rlo[ab];
            const short8 bh = *(const short8*)&ubh[(size_t)s << 9];
            const short8 bl = *(const short8*)&ubl[(size_t)s << 9];
            aH = MFMA_BF16(ah, bh, aH, 0, 0, 0);
            aM = MFMA_BF16(ah, bl, aM, 0, 0, 0);
            aL = MFMA_BF16(al, bh, aL, 0, 0, 0);
        }
        #pragma unroll
        for (int i = 0; i < 4; ++i)
            out[(size_t)(row0 + (quad << 2) + i) * PIX + (ot << 4) + l15] =
                (aH[i] + aM[i]) + aL[i];
    }
}

extern "C" void kernel_launch(void* const* d_in, const int* in_sizes, int n_in,
                              void* d_out, int out_size, void* d_ws, size_t ws_size,
                              hipStream_t stream) {
    const float* img = (const float*)d_in[0];  // [4096, 1024]
    const float* U   = (const float*)d_in[1];  // [1024, 256]
    float* out = (float*)d_out;                // [4096, 1024]

    float*          S     = (float*)d_ws;                       // 65536 f (256 KB)
    unsigned short* UGh   = (unsigned short*)((char*)d_ws + 262144);   // 512 KB
    unsigned short* UGl   = UGh + 262144;                              // 512 KB
    unsigned short* UtBh  = UGl + 262144;                              // 512 KB
    unsigned short* UtBl  = UtBh + 262144;                             // 512 KB
    unsigned long long* partials = (unsigned long long*)(UtBl + 262144); // 8*2*256 u64 = 32 KB

    k_prep<<<336, 256, 0, stream>>>(U, S, UGh, UGl, UtBh, UtBl, partials);

    // Regular launch: the kernel uses no grid-wide barrier (tagged-partials
    // protocol only); 256 blocks at 1/CU are all co-resident on 256 CUs.
    k_ista<<<dim3(NBLK), dim3(NTHR), 0, stream>>>(img, S, UGh, UGl, UtBh, UtBl,
                                                  out, partials);
}